// Round 16
// baseline (265.653 us; speedup 1.0000x reference)
//
#include <hip/hip_runtime.h>
#include <hip/hip_bf16.h>

#define D_DIM 512
#define EPS 1e-5f
#define BM 128
#define BN 128
#define BK 32
#define KT 16   // D_DIM / BK

typedef __attribute__((ext_vector_type(8))) short bf16x8;
typedef __attribute__((ext_vector_type(4))) float f32x4;

__device__ __forceinline__ unsigned short f2bf(float f) {
  unsigned int u = __float_as_uint(f);
  u += 0x7FFFu + ((u >> 16) & 1u);   // round-to-nearest-even
  return (unsigned short)(u >> 16);
}

// Fused prep: rows [0,N) from x -> Xbf/xnsq, rows [N,N+V) from w -> Ybf/ynsq.
__global__ __launch_bounds__(256) void prep_rows2(
    const float* __restrict__ x, const float* __restrict__ w,
    unsigned short* __restrict__ Xbf, unsigned short* __restrict__ Ybf,
    float* __restrict__ xnsq, float* __restrict__ ynsq, int N, int total)
{
  int row  = blockIdx.x * 4 + (threadIdx.x >> 6);
  int lane = threadIdx.x & 63;
  if (row >= total) return;

  const float* src; unsigned short* dst; float* nsq; int r;
  if (row < N) { src = x; dst = Xbf; nsq = xnsq; r = row; }
  else         { src = w; dst = Ybf; nsq = ynsq; r = row - N; }

  const float4* s = (const float4*)(src + (size_t)r * D_DIM);
  float4 v0 = s[lane];
  float4 v1 = s[lane + 64];
  float ss = v0.x*v0.x + v0.y*v0.y + v0.z*v0.z + v0.w*v0.w
           + v1.x*v1.x + v1.y*v1.y + v1.z*v1.z + v1.w*v1.w;
  #pragma unroll
  for (int off = 32; off; off >>= 1) ss += __shfl_xor(ss, off);

  float norm  = sqrtf(ss);
  float scale = fminf((1.0f - EPS) / (norm + 1e-10f), 1.0f);
  if (lane == 0) nsq[r] = ss * scale * scale;

  ushort4 o0, o1;
  o0.x = f2bf(v0.x * scale); o0.y = f2bf(v0.y * scale);
  o0.z = f2bf(v0.z * scale); o0.w = f2bf(v0.w * scale);
  o1.x = f2bf(v1.x * scale); o1.y = f2bf(v1.y * scale);
  o1.z = f2bf(v1.z * scale); o1.w = f2bf(v1.w * scale);

  ushort4* dp = (ushort4*)(dst + (size_t)r * D_DIM);
  dp[lane]      = o0;
  dp[lane + 64] = o1;
}

// 128x128 bf16 GEMM with ZERO-BARRIER wave-autonomous K-loop: each of 4 waves
// (2x2 of 64x64) stages its OWN A/B LDS region (ping-pong 2x8KB) and self-times
// via per-wave counted vmcnt. No s_barrier / __syncthreads anywhere in the
// kernel. XOR bank-swizzle both-sides, swapped MFMA operands, fused arccosh
// epilogue, coalesced nontemporal stores via per-wave LDS transpose.
__global__ __launch_bounds__(256, 2) void hyp_gemm(
    const unsigned short* __restrict__ Xbf, const unsigned short* __restrict__ Ybf,
    const float* __restrict__ xnsq, const float* __restrict__ ynsq,
    float* __restrict__ out, int N, int V)
{
  // [wave][buf][A 2048 shorts | B 2048 shorts] = 8 KB/buf, 64 KB total
  __shared__ __attribute__((aligned(16))) unsigned short lds[4][2][4096];

  int bid = blockIdx.x;
  // bm-inner traversal: 32 consecutive bids = one bn, all bm (4 blocks/XCD
  // share the B panel via L2; bn window of ~16 resident -> B/A L3-resident).
  int bm = bid & 31;           // 0..31
  int bn = bid >> 5;           // 0..249

  int tid  = threadIdx.x;
  int wid  = tid >> 6;
  int lane = tid & 63;
  int wm = wid >> 1, wn = wid & 1;   // 2x2 waves, each owns 64x64 of C

  size_t a_row0 = (size_t)bm * BM + wm * 64;   // this wave's A rows
  size_t b_row0 = (size_t)bn * BN + wn * 64;   // this wave's B rows

  // Wave-private staging: 8 chunks/lane (4 A + 4 B), wave-uniform LDS bases.
  // LDS chunk c (row=c>>2, slot=c&3) holds global k-chunk (c&3)^((row>>1)&3).
  auto STAGE = [&](int buf, int kt) {
    int k0 = kt * BK;
    char* base = (char*)&lds[wid][buf][0];
    #pragma unroll
    for (int j = 0; j < 4; ++j) {              // A: chunks c = j*64 + lane
      int c = j * 64 + lane;
      int row = c >> 2;
      int s = (c & 3) ^ ((row >> 1) & 3);
      const unsigned short* g = Xbf + (a_row0 + row) * D_DIM + k0 + s * 8;
      __builtin_amdgcn_global_load_lds(
          (const __attribute__((address_space(1))) void*)g,
          (__attribute__((address_space(3))) void*)(base + j * 1024), 16, 0, 0);
    }
    #pragma unroll
    for (int j = 0; j < 4; ++j) {              // B
      int c = j * 64 + lane;
      int row = c >> 2;
      int s = (c & 3) ^ ((row >> 1) & 3);
      const unsigned short* g = Ybf + (b_row0 + row) * D_DIM + k0 + s * 8;
      __builtin_amdgcn_global_load_lds(
          (const __attribute__((address_space(1))) void*)g,
          (__attribute__((address_space(3))) void*)(base + 4096 + j * 1024), 16, 0, 0);
    }
  };

  // Hoisted epilogue operands (oldest vm ops; forced complete by first vmcnt(8)).
  int jr = lane & 15;
  int h  = lane >> 4;
  float xnv[4], dxv[4];
  #pragma unroll
  for (int m = 0; m < 4; ++m) {
    float xn = xnsq[bm * BM + wm * 64 + m * 16 + jr];
    xnv[m] = xn; dxv[m] = 1.0f - xn;
  }
  f32x4 ynv[4], dyv[4];
  #pragma unroll
  for (int n = 0; n < 4; ++n) {
    f32x4 y4 = *(const f32x4*)&ynsq[bn * BN + wn * 64 + n * 16 + h * 4];
    ynv[n] = y4;
    dyv[n] = 1.0f - y4;
  }

  f32x4 acc[4][4] = {};
  int r = lane & 15;
  int slotoff = ((lane >> 4) ^ ((r >> 1) & 3)) * 8;   // swizzled chunk (shorts)

  // Prologue: stage tiles 0,1 into bufs 0,1 (8 loads each).
  STAGE(0, 0);
  STAGE(1, 1);

  // K-loop (no barriers): wait own vmcnt -> ds_read own buf -> lgkm fence ->
  // restage same buf with tile t+2 -> MFMA. Tile t+1's 8 loads stay in flight.
  #pragma unroll
  for (int t = 0; t < KT; ++t) {
    if (t == KT - 1) {
      asm volatile("s_waitcnt vmcnt(0)" ::: "memory");
    } else {
      asm volatile("s_waitcnt vmcnt(8)" ::: "memory");
    }
    __builtin_amdgcn_sched_barrier(0);

    const unsigned short* sbuf = &lds[wid][t & 1][0];
    bf16x8 a[4], b[4];
    #pragma unroll
    for (int m = 0; m < 4; ++m)
      a[m] = *(const bf16x8*)&sbuf[(m * 16 + r) * 32 + slotoff];
    #pragma unroll
    for (int n = 0; n < 4; ++n)
      b[n] = *(const bf16x8*)&sbuf[2048 + (n * 16 + r) * 32 + slotoff];

    // reads -> regs complete before overwriting this buf (rule 18 fence)
    asm volatile("s_waitcnt lgkmcnt(0)" ::: "memory");
    __builtin_amdgcn_sched_barrier(0);

    if (t + 2 < KT) STAGE(t & 1, t + 2);

    #pragma unroll
    for (int m = 0; m < 4; ++m)
      #pragma unroll
      for (int n = 0; n < 4; ++n)
        acc[m][n] = __builtin_amdgcn_mfma_f32_16x16x32_bf16(b[n], a[m], acc[m][n], 0, 0, 0);
  }

  // ---- Epilogue (wave-private, still no barriers) ----
  // acc[m][n][q]: x_row_local = lane&15, y_col_local = (lane>>4)*4 + q.
  float* epi = (float*)&lds[wid][0][0];   // own 8 KB buf0, reads retired

  float cmv[4];
  #pragma unroll
  for (int m = 0; m < 4; ++m) cmv[m] = 2.0f * __builtin_amdgcn_rcpf(dxv[m]);
  f32x4 rdy[4];
  #pragma unroll
  for (int n = 0; n < 4; ++n) {
    #pragma unroll
    for (int q = 0; q < 4; ++q) rdy[n][q] = __builtin_amdgcn_rcpf(dyv[n][q]);
  }

  size_t out_row0 = (size_t)bm * BM + wm * 64;
  int    out_col0 = bn * BN + wn * 64;

  #pragma unroll
  for (int m = 0; m < 4; ++m) {
    float xn = xnv[m], cm = cmv[m];
    #pragma unroll
    for (int n = 0; n < 4; ++n) {
      f32x4 f;
      #pragma unroll
      for (int q = 0; q < 4; ++q) {
        float dot  = acc[m][n][q];
        float sq   = fmaxf(xn + ynv[n][q] - 2.0f * dot, 0.0f);
        float dist = __builtin_amdgcn_sqrtf(sq);
        float arg  = fmaf(dist * cm, rdy[n][q], 1.0f);
        arg = fmaxf(arg, 1.0f + EPS);
        float t2 = __builtin_amdgcn_sqrtf(fmaf(arg, arg, -1.0f));
        f[q] = -__logf(arg + t2);   // -arccosh(arg)
      }
      *(f32x4*)&epi[jr * 68 + n * 16 + h * 4] = f;
    }
    // read back coalesced: 16 consecutive lanes = 256B contiguous of one row.
    #pragma unroll
    for (int k = 0; k < 4; ++k) {
      int xl = k * 4 + h;
      f32x4 f = *(const f32x4*)&epi[xl * 68 + jr * 4];
      size_t rg = out_row0 + m * 16 + xl;
      int    cg = out_col0 + jr * 4;
      __builtin_nontemporal_store(f, (f32x4*)(out + rg * (size_t)V + cg));
    }
  }
}

extern "C" void kernel_launch(void* const* d_in, const int* in_sizes, int n_in,
                              void* d_out, int out_size, void* d_ws, size_t ws_size,
                              hipStream_t stream) {
  const float* x = (const float*)d_in[0];   // hidden_states (B,S,D) f32
  const float* w = (const float*)d_in[1];   // weight (V,D) f32
  float* out = (float*)d_out;

  int N = in_sizes[0] / D_DIM;   // 4096
  int V = in_sizes[1] / D_DIM;   // 32000

  char* ws = (char*)d_ws;
  unsigned short* Xbf = (unsigned short*)ws;
  size_t xbf_bytes = (size_t)N * D_DIM * 2;
  unsigned short* Ybf = (unsigned short*)(ws + xbf_bytes);
  size_t ybf_bytes = (size_t)V * D_DIM * 2;
  float* xnsq = (float*)(ws + xbf_bytes + ybf_bytes);
  float* ynsq = xnsq + N;

  int total = N + V;
  prep_rows2<<<dim3((total + 3) / 4), dim3(256), 0, stream>>>(
      x, w, Xbf, Ybf, xnsq, ynsq, N, total);

  int nwg = (N / BM) * (V / BN);   // 32 * 250 = 8000
  hyp_gemm<<<dim3(nwg), dim3(256), 0, stream>>>(Xbf, Ybf, xnsq, ynsq, out, N, V);
}

// Round 17
// 228.102 us; speedup vs baseline: 1.1646x; 1.1646x over previous
//
#include <hip/hip_runtime.h>
#include <hip/hip_bf16.h>

#define D_DIM 512
#define EPS 1e-5f
#define BM 256
#define BN 128
#define BK 32
#define KT 16   // D_DIM / BK
#define SLOT_SHORTS (BM * BK + BN * BK)   // 12288 shorts = 24 KB

typedef __attribute__((ext_vector_type(8))) short bf16x8;
typedef __attribute__((ext_vector_type(4))) float f32x4;

__device__ __forceinline__ unsigned short f2bf(float f) {
  unsigned int u = __float_as_uint(f);
  u += 0x7FFFu + ((u >> 16) & 1u);   // round-to-nearest-even
  return (unsigned short)(u >> 16);
}

// Fused prep: rows [0,N) from x -> Xbf/xnsq, rows [N,N+V) from w -> Ybf/ynsq.
__global__ __launch_bounds__(256) void prep_rows2(
    const float* __restrict__ x, const float* __restrict__ w,
    unsigned short* __restrict__ Xbf, unsigned short* __restrict__ Ybf,
    float* __restrict__ xnsq, float* __restrict__ ynsq, int N, int total)
{
  int row  = blockIdx.x * 4 + (threadIdx.x >> 6);
  int lane = threadIdx.x & 63;
  if (row >= total) return;

  const float* src; unsigned short* dst; float* nsq; int r;
  if (row < N) { src = x; dst = Xbf; nsq = xnsq; r = row; }
  else         { src = w; dst = Ybf; nsq = ynsq; r = row - N; }

  const float4* s = (const float4*)(src + (size_t)r * D_DIM);
  float4 v0 = s[lane];
  float4 v1 = s[lane + 64];
  float ss = v0.x*v0.x + v0.y*v0.y + v0.z*v0.z + v0.w*v0.w
           + v1.x*v1.x + v1.y*v1.y + v1.z*v1.z + v1.w*v1.w;
  #pragma unroll
  for (int off = 32; off; off >>= 1) ss += __shfl_xor(ss, off);

  float norm  = sqrtf(ss);
  float scale = fminf((1.0f - EPS) / (norm + 1e-10f), 1.0f);
  if (lane == 0) nsq[r] = ss * scale * scale;

  ushort4 o0, o1;
  o0.x = f2bf(v0.x * scale); o0.y = f2bf(v0.y * scale);
  o0.z = f2bf(v0.z * scale); o0.w = f2bf(v0.w * scale);
  o1.x = f2bf(v1.x * scale); o1.y = f2bf(v1.y * scale);
  o1.z = f2bf(v1.z * scale); o1.w = f2bf(v1.w * scale);

  ushort4* dp = (ushort4*)(dst + (size_t)r * D_DIM);
  dp[lane]      = o0;
  dp[lane + 64] = o1;
}

// 256x128 bf16 GEMM, 512 threads / 8 waves (4x2 of 64x64), 3-slot LDS rotation
// with counted vmcnt, XOR bank-swizzle (both-sides: pre-swizzled global source
// for global_load_lds + swizzled ds_read), swapped MFMA operands, fused arccosh
// epilogue, coalesced nontemporal stores via LDS transpose.  [session best]
__global__ __launch_bounds__(512, 4) void hyp_gemm(
    const unsigned short* __restrict__ Xbf, const unsigned short* __restrict__ Ybf,
    const float* __restrict__ xnsq, const float* __restrict__ ynsq,
    float* __restrict__ out, int N, int V)
{
  // 3 slots x [A(8192 shorts) | B(4096 shorts)] = 24 KB/slot, 72 KB total
  __shared__ __attribute__((aligned(16))) unsigned short sAB[3][SLOT_SHORTS];

  int bid = blockIdx.x;
  // bn-major per-XCD traversal: XCD (bid&7) owns 2 consecutive bm rows; inner
  // order sweeps bn once, 2 bm back-to-back -> Ybf panel L2-hot, swept once.
  int local = bid >> 3;              // 0..499
  int bn = local >> 1;               // 0..249
  int bm = (bid & 7) * 2 + (local & 1);  // 0..15

  int tid  = threadIdx.x;
  int wid  = tid >> 6;
  int lane = tid & 63;
  int wm = wid >> 1, wn = wid & 1;   // 4x2 waves, each owns 64x64

  size_t a_row0 = (size_t)bm * BM;
  size_t b_row0 = (size_t)bn * BN;

  // Both-sides XOR swizzle: LDS slot s of row holds global chunk s ^ ((row>>1)&3).
  // Staging: linear LDS dest (chunk c at offset c*16B), pre-swizzled global src.
  auto STAGE = [&](int slot, int kt) {
    int k0 = kt * BK;
    char* base = (char*)&sAB[slot][0];
    #pragma unroll
    for (int i = 0; i < 2; ++i) {            // A: 1024 chunks, 2 per thread
      int c = i * 512 + tid;
      int row = c >> 2;
      int s = (c & 3) ^ ((c >> 3) & 3);
      const unsigned short* gA = Xbf + (a_row0 + row) * D_DIM + k0 + s * 8;
      char* lA = base + (size_t)(i * 512 + wid * 64) * 16;   // wave-uniform base
      __builtin_amdgcn_global_load_lds(
          (const __attribute__((address_space(1))) void*)gA,
          (__attribute__((address_space(3))) void*)lA, 16, 0, 0);
    }
    {                                        // B: 512 chunks, 1 per thread
      int c = tid;
      int row = c >> 2;
      int s = (c & 3) ^ ((c >> 3) & 3);
      const unsigned short* gB = Ybf + (b_row0 + row) * D_DIM + k0 + s * 8;
      char* lB = base + (size_t)(BM * BK) * 2 + (size_t)(wid * 64) * 16;
      __builtin_amdgcn_global_load_lds(
          (const __attribute__((address_space(1))) void*)gB,
          (__attribute__((address_space(3))) void*)lB, 16, 0, 0);
    }
  };

  // Hoisted epilogue operands (issued BEFORE staging: retired by iter-0 wait).
  int jr = lane & 15;       // x-row within 16-row slab (fragment col)
  int h  = lane >> 4;       // 0..3
  float xnv[4], dxv[4];
  #pragma unroll
  for (int m = 0; m < 4; ++m) {
    float xn = xnsq[bm * BM + wm * 64 + m * 16 + jr];
    xnv[m] = xn; dxv[m] = 1.0f - xn;
  }
  f32x4 ynv[4], dyv[4];
  #pragma unroll
  for (int n = 0; n < 4; ++n) {
    f32x4 y4 = *(const f32x4*)&ynsq[bn * BN + wn * 64 + n * 16 + h * 4];
    ynv[n] = y4;
    dyv[n] = 1.0f - y4;
  }

  f32x4 acc[4][4] = {};
  int r = lane & 15;
  int slotoff = ((lane >> 4) ^ ((r >> 1) & 3)) * 8;   // swizzled 16B-chunk, lane-const

  // Prologue: stage tiles 0 and 1 (3 loads each).
  STAGE(0, 0);
  STAGE(1, 1);

  // K-loop: wait(counted) -> barrier -> ds_read(slot t) -> stage(t+2) -> MFMA.
  // vmcnt(3) = one tile's 3 loads may stay in flight across the barrier.
  #pragma unroll
  for (int t = 0; t < KT; ++t) {
    if (t == KT - 1) {
      asm volatile("s_waitcnt vmcnt(0)" ::: "memory");
    } else {
      asm volatile("s_waitcnt vmcnt(3)" ::: "memory");
    }
    __builtin_amdgcn_sched_barrier(0);
    __builtin_amdgcn_s_barrier();
    __builtin_amdgcn_sched_barrier(0);

    const unsigned short* sA = &sAB[t % 3][0];
    const unsigned short* sB = sA + BM * BK;
    bf16x8 a[4], b[4];
    #pragma unroll
    for (int m = 0; m < 4; ++m)
      a[m] = *(const bf16x8*)&sA[(wm * 64 + m * 16 + r) * BK + slotoff];
    #pragma unroll
    for (int n = 0; n < 4; ++n)
      b[n] = *(const bf16x8*)&sB[(wn * 64 + n * 16 + r) * BK + slotoff];

    if (t + 2 < KT) STAGE((t + 2) % 3, t + 2);   // overwrites slot (t-1): safe post-barrier

    #pragma unroll
    for (int m = 0; m < 4; ++m)
      #pragma unroll
      for (int n = 0; n < 4; ++n)
        acc[m][n] = __builtin_amdgcn_mfma_f32_16x16x32_bf16(b[n], a[m], acc[m][n], 0, 0, 0);
  }

  // ---- Epilogue ----
  // Swapped layout: acc[m][n][q] = dot(x_row, y_col),
  //   x_row_local = lane&15, y_col_local = (lane>>4)*4 + q.
  __syncthreads();   // staging LDS dead -> reuse as per-wave f32 slab
  float* epi = (float*)&sAB[0][0] + wid * (16 * 68);   // 8 x 4.35 KB = 34.8 KB < 72 KB

  // Factored reciprocal: 1/(dx*dy+eps) ~= rcp(dx)*rcp(dy) (shift ~2e-5, negligible).
  float cmv[4];
  #pragma unroll
  for (int m = 0; m < 4; ++m) cmv[m] = 2.0f * __builtin_amdgcn_rcpf(dxv[m]);
  f32x4 rdy[4];
  #pragma unroll
  for (int n = 0; n < 4; ++n) {
    #pragma unroll
    for (int q = 0; q < 4; ++q) rdy[n][q] = __builtin_amdgcn_rcpf(dyv[n][q]);
  }

  size_t out_row0 = (size_t)bm * BM + wm * 64;
  int    out_col0 = bn * BN + wn * 64;

  #pragma unroll
  for (int m = 0; m < 4; ++m) {
    float xn = xnv[m], cm = cmv[m];
    #pragma unroll
    for (int n = 0; n < 4; ++n) {
      f32x4 f;
      #pragma unroll
      for (int q = 0; q < 4; ++q) {
        float dot  = acc[m][n][q];
        float sq   = fmaxf(xn + ynv[n][q] - 2.0f * dot, 0.0f);
        float dist = __builtin_amdgcn_sqrtf(sq);
        float arg  = fmaf(dist * cm, rdy[n][q], 1.0f);
        arg = fmaxf(arg, 1.0f + EPS);
        float t2 = __builtin_amdgcn_sqrtf(fmaf(arg, arg, -1.0f));
        f[q] = -__logf(arg + t2);   // -arccosh(arg)
      }
      *(f32x4*)&epi[jr * 68 + n * 16 + h * 4] = f;
    }
    // read back coalesced: 16 consecutive lanes = 256B contiguous of one row.
    #pragma unroll
    for (int k = 0; k < 4; ++k) {
      int xl = k * 4 + h;
      f32x4 f = *(const f32x4*)&epi[xl * 68 + jr * 4];
      size_t rg = out_row0 + m * 16 + xl;
      int    cg = out_col0 + jr * 4;
      __builtin_nontemporal_store(f, (f32x4*)(out + rg * (size_t)V + cg));
    }
  }
}

extern "C" void kernel_launch(void* const* d_in, const int* in_sizes, int n_in,
                              void* d_out, int out_size, void* d_ws, size_t ws_size,
                              hipStream_t stream) {
  const float* x = (const float*)d_in[0];   // hidden_states (B,S,D) f32
  const float* w = (const float*)d_in[1];   // weight (V,D) f32
  float* out = (float*)d_out;

  int N = in_sizes[0] / D_DIM;   // 4096
  int V = in_sizes[1] / D_DIM;   // 32000

  char* ws = (char*)d_ws;
  unsigned short* Xbf = (unsigned short*)ws;
  size_t xbf_bytes = (size_t)N * D_DIM * 2;
  unsigned short* Ybf = (unsigned short*)(ws + xbf_bytes);
  size_t ybf_bytes = (size_t)V * D_DIM * 2;
  float* xnsq = (float*)(ws + xbf_bytes + ybf_bytes);
  float* ynsq = xnsq + N;

  int total = N + V;
  prep_rows2<<<dim3((total + 3) / 4), dim3(256), 0, stream>>>(
      x, w, Xbf, Ybf, xnsq, ynsq, N, total);

  int nwg = (N / BM) * (V / BN);   // 16 * 250 = 4000
  hyp_gemm<<<dim3(nwg), dim3(512), 0, stream>>>(Xbf, Ybf, xnsq, ynsq, out, N, V);
}